// Round 4
// baseline (87.089 us; speedup 1.0000x reference)
//
#include <hip/hip_runtime.h>
#include <math.h>

#define B_ 8
#define BIGF 3.4e38f

typedef float f32x2 __attribute__((ext_vector_type(2)));
typedef float f32x4 __attribute__((ext_vector_type(4)));

// Guaranteed packed fp32 FMA: d.lo = a.lo*b.lo + c.lo; d.hi = a.hi*b.hi + c.hi.
// R3 post-mortem: __builtin_elementwise_fma on f32x2 was scalarized by ISel
// (neutral result, instr/pair stayed ~3.5). VOP3P v_pk_fma_f32 exists on
// gfx950; "v" constraint on a 64-bit ext-vector allocates an aligned VGPR
// pair; dst aliasing src is legal.
__device__ __forceinline__ f32x2 pk_fma(f32x2 a, f32x2 b, f32x2 c) {
    f32x2 d;
    asm("v_pk_fma_f32 %0, %1, %2, %3" : "=v"(d) : "v"(a), "v"(b), "v"(c));
    return d;
}

// ws layout (16-B aligned base):
//   packT  : B_*N float4 {x,y,z,|t|^2}
//   packS  : B_*M float4 {x,y,z,|s|^2}
//   minarr : B_*N uint rowmin + B_*M uint colmin (uint-ordered float d^2)

__global__ __launch_bounds__(256) void pack_kernel(
    const float* __restrict__ tar, const float* __restrict__ src,
    float4* __restrict__ packT, float4* __restrict__ packS,
    unsigned int* __restrict__ minarr, float* __restrict__ outp,
    int N, int M)
{
    const int i = blockIdx.x * 256 + threadIdx.x;
    const int nT = B_ * N, nS = B_ * M;
    if (i < nT) {
        float x = tar[3 * i], y = tar[3 * i + 1], z = tar[3 * i + 2];
        packT[i] = make_float4(x, y, z, fmaf(x, x, fmaf(y, y, z * z)));
    } else if (i < nT + nS) {
        int j = i - nT;
        float x = src[3 * j], y = src[3 * j + 1], z = src[3 * j + 2];
        packS[j] = make_float4(x, y, z, fmaf(x, x, fmaf(y, y, z * z)));
    }
    if (i < nT + nS) minarr[i] = 0x7F800000u;  // +inf
    if (i < 3) outp[i] = 0.f;                  // accuracy, complete, chamfer
}

// R4: ONLY change vs R3 = inline-asm v_pk_fma_f32 in the inner loop
// (clean single-variable experiment). Evidence trail:
//   R1 scalar-cache refetch: latency-bound, 93us. R2 readlane: VGPR=36
//   spill-bound, 41.3us @ VALUBusy 72%. R0/R3 (LDS broadcast, scalar fma):
//   ~28-30us at ~3.5 VALU instr/pair vs 12us lane-cycle floor -> the SIMD
//   ISSUE port is the wall (every wave64 VALU op = 2 issue-cy). pk_fma
//   halves the dominant instruction class: per 4 refs x query = 6 pk_fma
//   + 2 v_min3 = 2.0 instr/pair.
// Refs staged in LDS as SoA (one uniform ds_read_b128 per coordinate = 4
// refs, broadcast, conflict-free); query coeffs pre-splatted f32x2; BIGF
// tail pad makes the packed loop universally correct (padded refs yield
// d=BIGF, never the min). QPT=16 keeps DS subcritical: 8 waves/CU x 4 b128
// x 12cy = 384 cy/CU-round vs 512 VALU issue-cy/SIMD-round.
// Cross-block combine: distributed uint atomicMin (d^2 clamped >= 0).
template <int QPT, int CHUNK>
__global__ __launch_bounds__(256, 2) void minsq_kernel(
    const float4* __restrict__ packT, const float4* __restrict__ packS,
    unsigned int* __restrict__ minarr, int N, int M)
{
    const int z   = blockIdx.z;
    const int dir = (z >= B_) ? 1 : 0;
    const int b   = dir ? (z - B_) : z;
    const float4* __restrict__ qry = dir ? packS : packT;
    const float4* __restrict__ pts = dir ? packT : packS;
    const int K = dir ? M : N;   // query count
    const int L = dir ? N : M;   // reference count
    unsigned int* __restrict__ out =
        minarr + (dir ? (size_t)B_ * N : (size_t)0) + (size_t)b * K;

    const int base = blockIdx.y * CHUNK;
    if (base >= L) return;
    const int cnt = min(CHUNK, L - base);
    const float4* __restrict__ psrc = pts + (size_t)b * L + base;

    // SoA staging: x/y/z/w arrays so b128 reads give 4 refs per coordinate.
    __shared__ __align__(16) float sx[CHUNK], sy[CHUNK], sz[CHUNK], sw[CHUNK];
    const int t = threadIdx.x;
    for (int i = t; i < cnt; i += 256) {
        float4 p = psrc[i];
        sx[i] = p.x; sy[i] = p.y; sz[i] = p.z; sw[i] = p.w;
    }
    for (int i = cnt + t; i < CHUNK; i += 256) {       // BIGF-pad tail
        sx[i] = 0.f; sy[i] = 0.f; sz[i] = 0.f; sw[i] = BIGF;
    }
    __syncthreads();

    const int qbase = blockIdx.x * (256 * QPT);
    f32x2 qx[QPT], qy[QPT], qz[QPT];
    float qw[QPT], mn[QPT];
#pragma unroll
    for (int k = 0; k < QPT; ++k) {
        int qi = qbase + k * 256 + t;
        float ax = 0.f, ay = 0.f, az = 0.f, aw = 0.f;
        if (qi < K) {
            float4 q = qry[(size_t)b * K + qi];
            ax = -2.f * q.x; ay = -2.f * q.y; az = -2.f * q.z; aw = q.w;
        }
        qx[k].x = ax; qx[k].y = ax;
        qy[k].x = ay; qy[k].y = ay;
        qz[k].x = az; qz[k].y = az;
        qw[k] = aw;
        mn[k] = BIGF;
    }

    const f32x4* __restrict__ X4 = (const f32x4*)sx;
    const f32x4* __restrict__ Y4 = (const f32x4*)sy;
    const f32x4* __restrict__ Z4 = (const f32x4*)sz;
    const f32x4* __restrict__ W4 = (const f32x4*)sw;

#pragma unroll 2
    for (int j4 = 0; j4 < CHUNK / 4; ++j4) {
        f32x4 X = X4[j4], Y = Y4[j4], Z = Z4[j4], W = W4[j4];
        f32x2 x01; x01.x = X.x; x01.y = X.y;
        f32x2 x23; x23.x = X.z; x23.y = X.w;
        f32x2 y01; y01.x = Y.x; y01.y = Y.y;
        f32x2 y23; y23.x = Y.z; y23.y = Y.w;
        f32x2 z01; z01.x = Z.x; z01.y = Z.y;
        f32x2 z23; z23.x = Z.z; z23.y = Z.w;
        f32x2 w01; w01.x = W.x; w01.y = W.y;
        f32x2 w23; w23.x = W.z; w23.y = W.w;
#pragma unroll
        for (int k = 0; k < QPT; ++k) {
            f32x2 dA = pk_fma(qx[k], x01,
                       pk_fma(qy[k], y01,
                       pk_fma(qz[k], z01, w01)));
            f32x2 dB = pk_fma(qx[k], x23,
                       pk_fma(qy[k], y23,
                       pk_fma(qz[k], z23, w23)));
            mn[k] = fminf(fminf(dA.x, dA.y), mn[k]);   // v_min3_f32
            mn[k] = fminf(fminf(dB.x, dB.y), mn[k]);   // v_min3_f32
        }
    }

#pragma unroll
    for (int k = 0; k < QPT; ++k) {
        int qi = qbase + k * 256 + t;
        if (qi < K) {
            float d2 = fmaxf(mn[k] + qw[k], 0.f);  // clamp roundoff negatives
            atomicMin(&out[qi], __float_as_uint(d2));
        }
    }
}

// Merged reduce+finalize: 32 blocks stripe-sum sqrt of both regions, then 3
// scaled atomicAdds into d_out (zeroed by pack_kernel).
__global__ __launch_bounds__(256) void reduce_kernel(
    const unsigned int* __restrict__ minarr, float* __restrict__ outp,
    int N, int M)
{
    const int nt = B_ * N, ns = B_ * M;
    const int gid = blockIdx.x * 256 + threadIdx.x;
    const int stride = gridDim.x * 256;
    float s_t = 0.f, s_s = 0.f;
    for (int i = gid; i < nt; i += stride)
        s_t += sqrtf(__uint_as_float(minarr[i]));
    for (int i = gid; i < ns; i += stride)
        s_s += sqrtf(__uint_as_float(minarr[nt + i]));
#pragma unroll
    for (int off = 32; off > 0; off >>= 1) {
        s_t += __shfl_down(s_t, off);
        s_s += __shfl_down(s_s, off);
    }
    __shared__ float rt[4], rs[4];
    const int wid = threadIdx.x >> 6, lid = threadIdx.x & 63;
    if (lid == 0) { rt[wid] = s_t; rs[wid] = s_s; }
    __syncthreads();
    if (threadIdx.x == 0) {
        float ct = (rt[0] + rt[1] + rt[2] + rt[3]) / (float)nt;  // complete
        float ac = (rs[0] + rs[1] + rs[2] + rs[3]) / (float)ns;  // accuracy
        atomicAdd(&outp[0], ac);
        atomicAdd(&outp[1], ct);
        atomicAdd(&outp[2], 0.5f * (ac + ct));
    }
}

extern "C" void kernel_launch(void* const* d_in, const int* in_sizes, int n_in,
                              void* d_out, int out_size, void* d_ws, size_t ws_size,
                              hipStream_t stream) {
    const float* tar = (const float*)d_in[0];
    const float* src = (const float*)d_in[1];
    const int N = in_sizes[0] / (B_ * 3);
    const int M = in_sizes[1] / (B_ * 3);

    float4* packT = (float4*)d_ws;
    float4* packS = packT + (size_t)B_ * N;
    unsigned int* minarr = (unsigned int*)(packS + (size_t)B_ * M);
    float* outp = (float*)d_out;

    pack_kernel<<<dim3((B_ * (N + M) + 255) / 256), dim3(256), 0, stream>>>(
        tar, src, packT, packS, minarr, outp, N, M);

    constexpr int QPT = 16, CHUNK = 128;
    const int KL = (N > M) ? N : M;
    const int gx = (KL + 256 * QPT - 1) / (256 * QPT);   // 1
    const int gy = (KL + CHUNK - 1) / CHUNK;             // 32
    dim3 grid(gx, gy, 2 * B_);                            // 512 blocks
    minsq_kernel<QPT, CHUNK><<<grid, dim3(256), 0, stream>>>(
        packT, packS, minarr, N, M);

    reduce_kernel<<<dim3(32), dim3(256), 0, stream>>>(minarr, outp, N, M);
}